// Round 1
// 202.628 us; speedup vs baseline: 1.0277x; 1.0277x over previous
//
#include <hip/hip_runtime.h>
#include <hip/hip_bf16.h>

// Static problem dims
#define NS_    2
#define LQ_    1024
#define HIST_  1024
#define LK_    2048
#define NH_    32
#define NKVH_  8
#define HD_    128
#define BS_    64      // kv page size
#define BM_    128     // q rows per workgroup
#define MAXB_  32

typedef __attribute__((ext_vector_type(8))) short short8;
typedef __attribute__((ext_vector_type(4))) float f32x4;

#define VSTR 72   // prep-internal V transpose tile stride (16B-aligned rows)

static __device__ __forceinline__ unsigned short f2bf(float x) {
    __hip_bfloat16 h = __float2bfloat16(x);
    return *(unsigned short*)&h;
}

static __device__ __forceinline__ void cp16(const void* g, void* l) {
    __builtin_amdgcn_global_load_lds(
        (const __attribute__((address_space(1))) void*)g,
        (__attribute__((address_space(3))) void*)l, 16, 0, 0);
}

template<int CTRL>
static __device__ __forceinline__ float dppmax(float x) {
    int y = __builtin_amdgcn_update_dpp(0, __float_as_int(x), CTRL, 0xf, 0xf, true);
    return fmaxf(x, __int_as_float(y));
}

// ---------------- Pass 1: gather + fp32->bf16 + V-transpose into workspace ----------------
// Kb[grp][tok][d]  (bf16)   Vb[grp][d][tok]  (bf16, transposed); grp = seq*8+kvh
// One WG per (seq,kvh,blk); all 16 global loads issued before any dependent work (MLP).
__global__ __launch_bounds__(256)
void prep_kv(const float* __restrict__ kc, const float* __restrict__ vc,
             const int* __restrict__ bt,
             unsigned short* __restrict__ Kb, unsigned short* __restrict__ Vb)
{
    __shared__ __align__(16) unsigned short Vt[HD_ * VSTR];
    const int tid = threadIdx.x;
    const int gid = blockIdx.x;            // 512 = seq(2) x kvh(8) x blk(32)
    const int seq = gid >> 8;
    const int kvh = (gid >> 5) & 7;
    const int blk = gid & 31;
    const int ph  = bt[seq * MAXB_ + blk];
    const size_t src = ((size_t)ph * BS_ * NKVH_ + kvh) * HD_;   // float elements
    const int grp = seq * NKVH_ + kvh;
    const int t8 = tid >> 5, q32 = tid & 31;

    float4 kr[8], vr[8];
#pragma unroll
    for (int p = 0; p < 8; ++p)
        kr[p] = *(const float4*)(kc + src + (size_t)(p * 8 + t8) * (NKVH_ * HD_) + q32 * 4);
#pragma unroll
    for (int j = 0; j < 8; ++j)
        vr[j] = *(const float4*)(vc + src + (size_t)(t8 * 8 + j) * (NKVH_ * HD_) + q32 * 4);

    // K: cvt + contiguous store (wave writes 512 B runs)
#pragma unroll
    for (int p = 0; p < 8; ++p) {
        unsigned short u[4] = {f2bf(kr[p].x), f2bf(kr[p].y), f2bf(kr[p].z), f2bf(kr[p].w)};
        *(uint2*)(Kb + ((size_t)grp * LK_ + blk * BS_ + p * 8 + t8) * HD_ + q32 * 4) = *(const uint2*)u;
    }
    // V: register 4-wide transpose via LDS, then contiguous store
#pragma unroll
    for (int w2 = 0; w2 < 4; ++w2) {
        unsigned short row[8];
#pragma unroll
        for (int j = 0; j < 8; ++j) {
            float f = (w2 == 0) ? vr[j].x : (w2 == 1) ? vr[j].y : (w2 == 2) ? vr[j].z : vr[j].w;
            row[j] = f2bf(f);
        }
        *(short8*)&Vt[(q32 * 4 + w2) * VSTR + t8 * 8] = *(const short8*)row;
    }
    __syncthreads();
#pragma unroll
    for (int u = 0; u < 4; ++u) {
        const int c  = tid + 256 * u;      // 0..1023 chunks of 8 elements
        const int d  = c >> 3, ch = c & 7;
        uint4 x = *(const uint4*)&Vt[d * VSTR + ch * 8];
        *(uint4*)(Vb + ((size_t)grp * HD_ + d) * LK_ + blk * BS_ + ch * 8) = x;
    }
}

// ---------------- Pass 2: fused paged prefill attention ----------------
// 8 waves x 512 threads per WG (16 q-rows per wave). Same 80KB LDS -> still 2 WG/CU,
// but 16 waves/CU = 4 waves/SIMD: doubles latency-hiding for the ds_read->MFMA and
// softmax dependency chains that previously left ~47% of cycles idle.
// Double-buffered async staging: one barrier per iteration; cp16 for block b+1
// issues right after the barrier and has the whole compute(b) phase to land.
// XOR-chunk swizzle keeps all b128 frag reads conflict-free.
template<bool PREP>
__global__ __launch_bounds__(512, 4)
void paged_attn(const float* __restrict__ q,
                const unsigned short* __restrict__ Kb,
                const unsigned short* __restrict__ Vb,
                const float* __restrict__ kc,
                const float* __restrict__ vc,
                const int* __restrict__ bt,
                float* __restrict__ out)
{
    __shared__ __align__(16) unsigned short Ksh[2][BS_ * HD_];   // 2 x 16384 B
    __shared__ __align__(16) unsigned short Vsh[2][HD_ * BS_];   // 2 x 16384 B
    __shared__ __align__(16) unsigned short Psh[BM_ * BS_];      // 16384 B

    const int tid  = threadIdx.x;
    const int w    = tid >> 6;             // 0..7
    const int lane = tid & 63;
    const int n    = lane & 15;
    const int q4   = lane >> 4;

    // XCD-aware decode (gid%8 = kvh pins KV slab to one XCD's L2) + balanced tile pairing:
    // consecutive slots get tiles (t, 7-t) so co-resident WGs sum to equal work.
    const int gid  = blockIdx.x;           // 512
    const int kvh  = gid & 7;
    const int slot = gid >> 3;
    const int seq  = slot >> 5;
    const int sub  = slot & 31;
    const int e    = sub & 1;
    const int t3   = (sub >> 1) & 7;
    const int hp   = sub >> 4;
    const int head = kvh * 4 + hp * 2 + e;
    const int m0   = (e ? (7 - t3) : t3) * BM_;
    const int r0   = m0 + w * 16;          // this wave's 16 q-rows
    const int grp  = seq * NKVH_ + kvh;

    // Q fragments fp32 -> bf16, pre-scaled by 1/sqrt(128)*log2(e): A[m=lane&15][k=quad*8+j]
    const float SC = 0.08838834764831845f * 1.4426950408889634f;
    short8 qf[4];
    {
        const size_t base = ((size_t)((seq * LQ_ + r0 + n) * NH_ + head)) * HD_;
#pragma unroll
        for (int c = 0; c < 4; ++c) {
            float4 a = *(const float4*)(q + base + c * 32 + q4 * 8);
            float4 b = *(const float4*)(q + base + c * 32 + q4 * 8 + 4);
            unsigned short u[8] = {f2bf(a.x * SC), f2bf(a.y * SC), f2bf(a.z * SC), f2bf(a.w * SC),
                                   f2bf(b.x * SC), f2bf(b.y * SC), f2bf(b.z * SC), f2bf(b.w * SC)};
            qf[c] = *(const short8*)u;
        }
    }

    f32x4 acc[8];
    f32x4 lf = (f32x4){0.f, 0.f, 0.f, 0.f};
    float mrow[4];
#pragma unroll
    for (int dt = 0; dt < 8; ++dt) acc[dt] = (f32x4){0.f, 0.f, 0.f, 0.f};
#pragma unroll
    for (int r = 0; r < 4; ++r) mrow[r] = -1e30f;

    const int nb = (HIST_ + m0 + BM_ - 1) / BS_ + 1;
    const unsigned short* kSrc = Kb + (size_t)grp * LK_ * HD_;
    const unsigned short* vSrc = Vb + (size_t)grp * HD_ * LK_;

    // async staging: source address carries the XOR swizzle; LDS dest is wave-uniform + lane*16.
    // 8 waves: each stages 2 K cp16 (8 rows) + 2 V cp16 (16 dims).
    auto issue = [&](int b, int buf) {
#pragma unroll
        for (int j = 0; j < 2; ++j) {
            const int row = w * 8 + j * 4 + (lane >> 4);
            const int c8  = (lane & 15) ^ (row & 15);
            cp16(kSrc + ((size_t)b * BS_ + row) * HD_ + c8 * 8, &Ksh[buf][(w * 8 + j * 4) * HD_]);
        }
#pragma unroll
        for (int j = 0; j < 2; ++j) {
            const int d  = w * 16 + j * 8 + (lane >> 3);
            const int c8 = (lane & 7) ^ (d & 7);
            cp16(vSrc + (size_t)d * LK_ + b * BS_ + c8 * 8, &Vsh[buf][(w * 16 + j * 8) * BS_]);
        }
    };

    if constexpr (PREP) issue(0, 0);
    short8 ones;
#pragma unroll
    for (int j = 0; j < 8; ++j) ones[j] = (short)0x3F80;

    for (int b = 0; b < nb; ++b) {
        const int cur = PREP ? (b & 1) : 0;
        __syncthreads();   // drains cp16 for buf[cur]; all waves done reading buf[1^cur]
        if constexpr (PREP) {
            if (b + 1 < nb) issue(b + 1, 1 ^ cur);
        } else {
            // fallback: direct fp32 gather + cvt into swizzled layout (2-barrier structure)
            const int ph = bt[seq * MAXB_ + b];
            const size_t src = ((size_t)ph * BS_ * NKVH_ + kvh) * HD_;
#pragma unroll
            for (int j = 0; j < 2; ++j) {
                const int row = w * 8 + j * 4 + (lane >> 4);
                const int c8  = (lane & 15) ^ (row & 15);
                float4 a = *(const float4*)(kc + src + (size_t)row * (NKVH_ * HD_) + c8 * 8);
                float4 b2 = *(const float4*)(kc + src + (size_t)row * (NKVH_ * HD_) + c8 * 8 + 4);
                unsigned short u[8] = {f2bf(a.x), f2bf(a.y), f2bf(a.z), f2bf(a.w),
                                       f2bf(b2.x), f2bf(b2.y), f2bf(b2.z), f2bf(b2.w)};
                *(short8*)&Ksh[0][row * HD_ + (lane & 15) * 8] = *(const short8*)u;
            }
#pragma unroll
            for (int j = 0; j < 2; ++j) {
                const int d  = w * 16 + j * 8 + (lane >> 3);
                const int c8 = (lane & 7) ^ (d & 7);
                unsigned short u[8];
#pragma unroll
                for (int i2 = 0; i2 < 8; ++i2)
                    u[i2] = f2bf(vc[src + (size_t)(c8 * 8 + i2) * (NKVH_ * HD_) + d]);
                *(short8*)&Vsh[0][d * BS_ + (lane & 7) * 8] = *(const short8*)u;
            }
            __syncthreads();
        }

        if (64 * b <= HIST_ + r0 + 15) {
            // ---- S = Q K^T (pre-scaled) ----
            f32x4 s[4];
#pragma unroll
            for (int kt = 0; kt < 4; ++kt) s[kt] = (f32x4){0.f, 0.f, 0.f, 0.f};
            __builtin_amdgcn_s_setprio(1);
#pragma unroll
            for (int kt = 0; kt < 4; ++kt) {
#pragma unroll
                for (int c = 0; c < 4; ++c) {
                    short8 kf = *(const short8*)&Ksh[cur][(kt * 16 + n) * HD_ + (((c * 4 + q4) ^ n) << 3)];
                    s[kt] = __builtin_amdgcn_mfma_f32_16x16x32_bf16(qf[c], kf, s[kt], 0, 0, 0);
                }
            }
            __builtin_amdgcn_s_setprio(0);

            const bool needMask = (64 * b + 63 > HIST_ + r0);
            float mx[4], al[4];
#pragma unroll
            for (int r = 0; r < 4; ++r) mx[r] = -1e30f;
#pragma unroll
            for (int kt = 0; kt < 4; ++kt) {
#pragma unroll
                for (int r = 0; r < 4; ++r) {
                    float t = s[kt][r];
                    if (needMask) {
                        const int key = b * 64 + kt * 16 + n;
                        const int row = r0 + q4 * 4 + r;
                        if (key > HIST_ + row) t = -1e30f;
                    }
                    s[kt][r] = t;
                    mx[r] = fmaxf(mx[r], t);
                }
            }
            // 16-lane row-max via DPP (VALU pipe)
#pragma unroll
            for (int r = 0; r < 4; ++r) {
                mx[r] = dppmax<0xB1>(mx[r]);    // quad_perm xor1
                mx[r] = dppmax<0x4E>(mx[r]);    // quad_perm xor2
                mx[r] = dppmax<0x124>(mx[r]);   // row_ror:4
                mx[r] = dppmax<0x128>(mx[r]);   // row_ror:8
                const float mn = fmaxf(mrow[r], mx[r]);
                al[r] = __builtin_amdgcn_exp2f(mrow[r] - mn);
                mrow[r] = mn;
            }
            // P (bf16) -> LDS, C-layout -> swizzled row-major [row][key]
            const int rbase = w * 16 + q4 * 4;
#pragma unroll
            for (int kt = 0; kt < 4; ++kt) {
                const int cb = kt * 2 + (n >> 3);
                const int ci = n & 7;
#pragma unroll
                for (int r = 0; r < 4; ++r) {
                    const int row = rbase + r;
                    const float p = __builtin_amdgcn_exp2f(s[kt][r] - mrow[r]);
                    Psh[row * BS_ + ((cb ^ (row & 7)) << 3) + ci] = f2bf(p);
                }
            }
            if (__any(al[0] != 1.f || al[1] != 1.f || al[2] != 1.f || al[3] != 1.f)) {
#pragma unroll
                for (int dt = 0; dt < 8; ++dt)
#pragma unroll
                    for (int r = 0; r < 4; ++r) acc[dt][r] *= al[r];
#pragma unroll
                for (int r = 0; r < 4; ++r) lf[r] *= al[r];
            }
            // ---- O += P V ; l += P 1 ----
            __builtin_amdgcn_s_setprio(1);
#pragma unroll
            for (int ks = 0; ks < 2; ++ks) {
                short8 pa = *(const short8*)&Psh[(w * 16 + n) * BS_ + (((ks * 4 + q4) ^ (n & 7)) << 3)];
                lf = __builtin_amdgcn_mfma_f32_16x16x32_bf16(pa, ones, lf, 0, 0, 0);
#pragma unroll
                for (int dt = 0; dt < 8; ++dt) {
                    short8 vf = *(const short8*)&Vsh[cur][(dt * 16 + n) * BS_ + (((ks * 4 + q4) ^ (n & 7)) << 3)];
                    acc[dt] = __builtin_amdgcn_mfma_f32_16x16x32_bf16(pa, vf, acc[dt], 0, 0, 0);
                }
            }
            __builtin_amdgcn_s_setprio(0);
        }
    }

    // epilogue: O = acc / l (fp32 out)
    {
        float rl[4];
#pragma unroll
        for (int r = 0; r < 4; ++r) rl[r] = 1.0f / lf[r];
#pragma unroll
        for (int dt = 0; dt < 8; ++dt)
#pragma unroll
            for (int r = 0; r < 4; ++r) {
                const int row = r0 + q4 * 4 + r;
                out[((size_t)((seq * LQ_ + row) * NH_ + head)) * HD_ + dt * 16 + n] = acc[dt][r] * rl[r];
            }
    }
}

extern "C" void kernel_launch(void* const* d_in, const int* in_sizes, int n_in,
                              void* d_out, int out_size, void* d_ws, size_t ws_size,
                              hipStream_t stream) {
    const float* q  = (const float*)d_in[0];
    const float* kc = (const float*)d_in[1];
    const float* vc = (const float*)d_in[2];
    const int*   bt = (const int*)d_in[5];
    float*      out = (float*)d_out;
    (void)in_sizes; (void)n_in; (void)out_size;

    const size_t kb_elems = (size_t)NS_ * NKVH_ * LK_ * HD_;        // 4.19M
    const size_t need = kb_elems * 2 * sizeof(unsigned short);      // 16.78 MB
    if (ws_size >= need) {
        unsigned short* Kb = (unsigned short*)d_ws;
        unsigned short* Vb = Kb + kb_elems;
        prep_kv<<<512, 256, 0, stream>>>(kc, vc, bt, Kb, Vb);
        paged_attn<true><<<512, 512, 0, stream>>>(q, Kb, Vb, kc, vc, bt, out);
    } else {
        paged_attn<false><<<512, 512, 0, stream>>>(q, nullptr, nullptr, kc, vc, bt, out);
    }
}